// Round 17
// baseline (68.815 us; speedup 1.0000x reference)
//
#include <hip/hip_runtime.h>
#include <hip/hip_bf16.h>
#include <stdint.h>

#define NB 8192
#define DK 256
// gamma * log2(e): epilogue uses native exp2
#define GSCALE 14.426950408889634f

typedef short short8 __attribute__((ext_vector_type(8)));
typedef float f32x16 __attribute__((ext_vector_type(16)));

__device__ __forceinline__ unsigned short f32_to_bf16(float f) {
  uint32_t u = __builtin_bit_cast(uint32_t, f);
  u += 0x7FFFu + ((u >> 16) & 1u);   // RNE
  return (unsigned short)(u >> 16);
}

// Normalize (gamma*log2e folded into e side) AND write in PACKED 32x32x16
// MFMA-fragment layout: fragment (row-panel p = r>>5, kslice = k>>4) is a
// contiguous 1-KB chunk; lane l owns bytes l*16..+16 = row p*32+(r&31),
// k = kslice*16 + (l>>5)*8 .. +8.  packed_byte(r,k) =
//   (r>>5)*16384 + (k>>4)*1024 + ((k>>3)&1)*512 + (r&31)*16 + (k&7)*2.
// Lane l holds k = 4l..4l+3 -> one 8-B store.
// Blocks 0..15 also zero d_out (replaces hipMemsetAsync).
__global__ __launch_bounds__(256) void normpack_kernel(const float* __restrict__ e,
                                                       const float* __restrict__ v,
                                                       unsigned short* __restrict__ apk,
                                                       unsigned short* __restrict__ vpk,
                                                       float* __restrict__ out) {
  if (blockIdx.x < 16) {
    float4 z = {0.f, 0.f, 0.f, 0.f};
    reinterpret_cast<float4*>(out)[blockIdx.x * 256 + threadIdx.x] = z;
  }
  int wave = threadIdx.x >> 6;
  int lane = threadIdx.x & 63;
  int row = blockIdx.x * 4 + wave;          // 0..16383
  const float* src;
  unsigned short* dstbase;
  float mul;
  if (row < NB) {
    src = e + (size_t)row * DK; dstbase = apk; mul = GSCALE;
  } else {
    row -= NB;
    src = v + (size_t)row * DK; dstbase = vpk; mul = 1.0f;
  }
  float4 x = reinterpret_cast<const float4*>(src)[lane];   // k = 4*lane .. +3
  float ss = x.x * x.x + x.y * x.y + x.z * x.z + x.w * x.w;
  #pragma unroll
  for (int off = 32; off >= 1; off >>= 1) ss += __shfl_xor(ss, off);
  float s = mul / fmaxf(sqrtf(ss), 1e-8f);
  ushort4 o;
  o.x = f32_to_bf16(x.x * s);
  o.y = f32_to_bf16(x.y * s);
  o.z = f32_to_bf16(x.z * s);
  o.w = f32_to_bf16(x.w * s);
  size_t off = (size_t)(row >> 5) * 16384 + (size_t)(lane >> 2) * 1024 +
               ((lane >> 1) & 1) * 512 + (row & 31) * 16 + (lane & 1) * 8;
  *reinterpret_cast<ushort4*>((char*)dstbase + off) = o;
}

// R16 structure ported to 32x32x16 MFMA: same 64x64 wave tile / 64x256 block
// (traffic invariant) but (a) MFMA pipe 17% faster (m119: 8.07cyc/32kFLOP),
// (b) B-ring 48->32 regs + af 16->8 => ~124 unified regs -> 4 waves/SIMD
// (launch_bounds(256,4)) -- the TLP the latency profile demands. 16 K-steps,
// ring depth 4 (slack ~260cyc > L2 latency), counted prologue vmcnt(8)
// (waits only the 8 A-glds; 8 B prologue loads fly through the barrier),
// setprio around the MFMA cluster, no in-loop barriers, fully static body.
__global__ __launch_bounds__(256, 4) void score_kernel(const unsigned short* __restrict__ apk,
                                                       const unsigned short* __restrict__ vpk,
                                                       float* __restrict__ out) {
  __shared__ unsigned short As[16384];      // 32 KB packed A panel (2 x 16 KB)
  __shared__ float rowsum[4][64];           // 1 KB

  const int tid = threadIdx.x;
  const int w = tid >> 6;          // 0..3 (64-col group within block)
  const int lane = tid & 63;
  const int l31 = lane & 31;
  const int hi = lane >> 5;        // 0..1

  // 4096 blocks: xcd = id&7; per XCD 4 colblks (512 KB B hot-set, L2-resident),
  // consecutive t walk rowblks within a colblk.
  int id = blockIdx.x;
  int xcd = id & 7;
  int t = id >> 3;                      // 0..511
  int colblk = (xcd << 2) | (t & 3);    // 0..31  (256-col strip)
  int rowblk = t >> 2;                  // 0..127 (64-row panel)

  // ---- Stage A panel: 32 KB, pure linear copy of packed fragments ----
  const char* aP = (const char*)apk + (size_t)rowblk * 32768;
  #pragma unroll
  for (int u = 0; u < 8; ++u) {
    int chunk = w * 8 + u;                     // 0..31 (1-KB fragments)
    const char* src = aP + chunk * 1024 + lane * 16;
    unsigned short* dst = &As[chunk * 512];
    __builtin_amdgcn_global_load_lds((const __attribute__((address_space(1))) uint32_t*)src,
                                     (__attribute__((address_space(3))) uint32_t*)dst, 16, 0, 0);
  }
  __builtin_amdgcn_sched_barrier(0);   // pin issue order: glds first, B loads after

  // ---- B ring prologue: wave's 2 col-panels (cp = colblk*8 + w*2 + n2, 16 KB
  //      each); frag byte = n2*16384 + ks*1024; ks = 0..3 in flight (8 loads) ----
  const char* pb = (const char*)vpk + (size_t)(colblk * 8 + w * 2) * 16384 + lane * 16;

  short8 S[4][2];
  #pragma unroll
  for (int s = 0; s < 4; ++s) {
    S[s][0] = *(const short8*)(pb + s * 1024);
    S[s][1] = *(const short8*)(pb + 16384 + s * 1024);
  }

  // wait ONLY the 8 A-glds (oldest 8 of 16 outstanding); B loads stay in flight
  asm volatile("s_waitcnt vmcnt(8)" ::: "memory");
  __builtin_amdgcn_s_barrier();
  asm volatile("" ::: "memory");

  f32x16 acc[2][2];
  #pragma unroll
  for (int m = 0; m < 2; ++m)
    #pragma unroll
    for (int n = 0; n < 2; ++n)
      #pragma unroll
      for (int q = 0; q < 16; ++q)
        acc[m][n][q] = 0.0f;

  // ---- K loop: 16 static steps, no barriers. 4-deep ring: step ks consumes
  //      S[ks&3]; refilled for step ks+4. ----
  #pragma unroll
  for (int ks = 0; ks < 16; ++ks) {
    short8 af0 = *(const short8*)((const char*)As + ks * 1024 + lane * 16);
    short8 af1 = *(const short8*)((const char*)As + 16384 + ks * 1024 + lane * 16);
    __builtin_amdgcn_s_setprio(1);
    acc[0][0] = __builtin_amdgcn_mfma_f32_32x32x16_bf16(af0, S[ks & 3][0], acc[0][0], 0, 0, 0);
    acc[0][1] = __builtin_amdgcn_mfma_f32_32x32x16_bf16(af0, S[ks & 3][1], acc[0][1], 0, 0, 0);
    acc[1][0] = __builtin_amdgcn_mfma_f32_32x32x16_bf16(af1, S[ks & 3][0], acc[1][0], 0, 0, 0);
    acc[1][1] = __builtin_amdgcn_mfma_f32_32x32x16_bf16(af1, S[ks & 3][1], acc[1][1], 0, 0, 0);
    __builtin_amdgcn_s_setprio(0);
    if (ks < 12) {                             // refill consumed slot for ks+4
      S[ks & 3][0] = *(const short8*)(pb + (ks + 4) * 1024);
      S[ks & 3][1] = *(const short8*)(pb + 16384 + (ks + 4) * 1024);
    }
  }

  // ---- epilogue: E = exp2(acc); rows -> LDS merge, cols -> atomics.
  // 32x32 C/D layout (m74/m101): col = n2*32 + l31,
  // row = m2*32 + (g&3) + 8*(g>>2) + 4*hi.
  float colpart[2] = {0.f, 0.f};

  #pragma unroll
  for (int m2 = 0; m2 < 2; ++m2) {
    float rowp[16];
    #pragma unroll
    for (int g = 0; g < 16; ++g) {
      float e0 = __builtin_amdgcn_exp2f(acc[m2][0][g]);
      float e1 = __builtin_amdgcn_exp2f(acc[m2][1][g]);
      colpart[0] += e0;
      colpart[1] += e1;
      rowp[g] = e0 + e1;
    }
    // row sums: reduce over the 32 cols (lanes of this hi-half)
    #pragma unroll
    for (int g = 0; g < 16; ++g) {
      float rs = rowp[g];
      rs += __shfl_xor(rs, 1);
      rs += __shfl_xor(rs, 2);
      rs += __shfl_xor(rs, 4);
      rs += __shfl_xor(rs, 8);
      rs += __shfl_xor(rs, 16);
      if (l31 == g) {
        rowsum[w][m2 * 32 + (g & 3) + 8 * (g >> 2) + 4 * hi] = rs;
      }
    }
  }

  // col sums: colpart[n2] covers this hi-half's 32 rows; xor 32 adds the other
  #pragma unroll
  for (int n2 = 0; n2 < 2; ++n2) {
    float cs = colpart[n2];
    cs += __shfl_xor(cs, 32);
    if (hi == n2) {
      atomicAdd(&out[NB + colblk * 256 + w * 64 + n2 * 32 + l31], cs);
    }
  }

  __syncthreads();
  // rows: merge the 4 waves' copies (same 64 rows), one atomic per row
  if (tid < 64) {
    float s = rowsum[0][tid] + rowsum[1][tid] + rowsum[2][tid] + rowsum[3][tid];
    atomicAdd(&out[rowblk * 64 + tid], s);
  }
}

extern "C" void kernel_launch(void* const* d_in, const int* in_sizes, int n_in,
                              void* d_out, int out_size, void* d_ws, size_t ws_size,
                              hipStream_t stream) {
  const float* e = (const float*)d_in[0];
  const float* v = (const float*)d_in[1];
  float* out = (float*)d_out;
  unsigned short* apk = (unsigned short*)d_ws;                 // 4 MiB packed e
  unsigned short* vpk = apk + (size_t)NB * DK;                 // 4 MiB packed v
  hipLaunchKernelGGL(normpack_kernel, dim3((2 * NB) / 4), dim3(256), 0, stream, e, v, apk, vpk, out);
  hipLaunchKernelGGL(score_kernel, dim3(4096), dim3(256), 0, stream, apk, vpk, out);
}

// Round 19
// 55.773 us; speedup vs baseline: 1.2338x; 1.2338x over previous
//
#include <hip/hip_runtime.h>
#include <hip/hip_bf16.h>
#include <stdint.h>

#define NB 8192
#define DK 256
// gamma * log2(e): epilogue uses native exp2
#define GSCALE 14.426950408889634f

typedef short short8 __attribute__((ext_vector_type(8)));
typedef float f32x4 __attribute__((ext_vector_type(4)));

__device__ __forceinline__ unsigned short f32_to_bf16(float f) {
  uint32_t u = __builtin_bit_cast(uint32_t, f);
  u += 0x7FFFu + ((u >> 16) & 1u);   // RNE
  return (unsigned short)(u >> 16);
}

// Normalize (gamma*log2e folded into e side) AND write in PACKED MFMA-fragment
// layout (16x16x32 shape): fragment (row-panel p = r>>4, ks = k>>5) is a
// contiguous 1-KB chunk; lane l owns bytes l*16..+16.
// packed_byte(r,k) = (r>>4)*8192 + (k>>5)*1024 + ((k>>3)&3)*256 + (r&15)*16 + (k&7)*2.
// Blocks 0..15 also zero d_out (replaces hipMemsetAsync).
__global__ __launch_bounds__(256) void normpack_kernel(const float* __restrict__ e,
                                                       const float* __restrict__ v,
                                                       unsigned short* __restrict__ apk,
                                                       unsigned short* __restrict__ vpk,
                                                       float* __restrict__ out) {
  if (blockIdx.x < 16) {
    float4 z = {0.f, 0.f, 0.f, 0.f};
    reinterpret_cast<float4*>(out)[blockIdx.x * 256 + threadIdx.x] = z;
  }
  int wave = threadIdx.x >> 6;
  int lane = threadIdx.x & 63;
  int row = blockIdx.x * 4 + wave;          // 0..16383
  const float* src;
  unsigned short* dstbase;
  float mul;
  if (row < NB) {
    src = e + (size_t)row * DK; dstbase = apk; mul = GSCALE;
  } else {
    row -= NB;
    src = v + (size_t)row * DK; dstbase = vpk; mul = 1.0f;
  }
  float4 x = reinterpret_cast<const float4*>(src)[lane];   // k = 4*lane .. +3
  float ss = x.x * x.x + x.y * x.y + x.z * x.z + x.w * x.w;
  #pragma unroll
  for (int off = 32; off >= 1; off >>= 1) ss += __shfl_xor(ss, off);
  float s = mul / fmaxf(sqrtf(ss), 1e-8f);
  ushort4 o;
  o.x = f32_to_bf16(x.x * s);
  o.y = f32_to_bf16(x.y * s);
  o.z = f32_to_bf16(x.z * s);
  o.w = f32_to_bf16(x.w * s);
  size_t off = (size_t)(row >> 4) * 8192 + (size_t)(lane >> 3) * 1024 +
               ((lane >> 1) & 3) * 256 + (row & 15) * 16 + (lane & 1) * 8;
  *reinterpret_cast<ushort4*>((char*)dstbase + off) = o;
}

// R18 structure with the B-panel addressing bug FIXED: panel index for a
// 512-col strip is col>>4 = colblk*32 + j*16 + w*4 + n  (R18 wrongly used
// colblk*64 and +32 panels per tile -> OOB reads, absmax 1088).
// Core = R16 (best clean round: 16x16 shape, ring 3, counted vmcnt(12)
// prologue, setprio, no in-loop barriers) x 2 sequential col-tiles per
// block, per-tile ring re-init (no cross-tile register carries), tile-1
// ring fill hidden under tile-0's pure-VALU/LDS epilogue, global atomics
// only in the tail burst. Block = 64 rows x 512 cols, 4 waves; grid 2048.
__global__ __launch_bounds__(256, 3) void score_kernel(const unsigned short* __restrict__ apk,
                                                       const unsigned short* __restrict__ vpk,
                                                       float* __restrict__ out) {
  __shared__ unsigned short As[16384];      // 32 KB packed A panel
  __shared__ float colsum[512];             // 2 KB
  __shared__ float rowsum[4][64];           // 1 KB

  const int tid = threadIdx.x;
  const int w = tid >> 6;          // 0..3 (64-col group within each tile)
  const int lane = tid & 63;
  const int lo16 = lane & 15;
  const int q4 = lane >> 4;        // 0..3

  // 2048 blocks: xcd = id&7; 2 colblks per XCD -> B hot-set 512 KB, L2-resident;
  // consecutive t walk rowblks within a colblk (A panel L2-reused).
  int id = blockIdx.x;
  int xcd = id & 7;
  int t = id >> 3;                      // 0..255
  int colblk = (xcd << 1) | (t & 1);    // 0..15  (512-col strip)
  int rowblk = t >> 1;                  // 0..127 (64-row panel)

  // ---- Stage A panel: 32 KB, pure linear copy of packed fragments ----
  const char* aP = (const char*)apk + (size_t)rowblk * 32768;
  #pragma unroll
  for (int u = 0; u < 8; ++u) {
    int chunk = w * 8 + u;                     // 0..31 (1-KB fragments)
    const char* src = aP + chunk * 1024 + lane * 16;
    unsigned short* dst = &As[chunk * 512];
    __builtin_amdgcn_global_load_lds((const __attribute__((address_space(1))) uint32_t*)src,
                                     (__attribute__((address_space(3))) uint32_t*)dst, 16, 0, 0);
  }
  __builtin_amdgcn_sched_barrier(0);   // pin issue order: glds first, B loads after

  // ---- B ring prologue (tile 0): wave's 4 col-panels, ks = 0,1,2 in flight ----
  // Tile j cols: colblk*512 + j*256 + w*64 + n*16; panel = col>>4
  //            = colblk*32 + j*16 + w*4 + n   (8192 B per panel).
  const char* pb0 = (const char*)vpk + (size_t)(colblk * 32 + w * 4) * 8192 + lane * 16;
  const char* pb1 = pb0 + 16 * 8192;   // tile 1 base (+256 cols = 16 panels)

  short8 S[3][4];
  #pragma unroll
  for (int s = 0; s < 3; ++s)
    #pragma unroll
    for (int n = 0; n < 4; ++n)
      S[s][n] = *(const short8*)(pb0 + n * 8192 + s * 1024);

  // wait ONLY the 8 A-glds (oldest 8 of 20 outstanding); B loads stay in flight
  asm volatile("s_waitcnt vmcnt(12)" ::: "memory");
  __builtin_amdgcn_s_barrier();
  asm volatile("" ::: "memory");

  #pragma unroll
  for (int j = 0; j < 2; ++j) {
    const char* pb = (j == 0) ? pb0 : pb1;

    f32x4 acc[4][4];
    #pragma unroll
    for (int m = 0; m < 4; ++m)
      #pragma unroll
      for (int n = 0; n < 4; ++n)
        #pragma unroll
        for (int q = 0; q < 4; ++q)
          acc[m][n][q] = 0.0f;

    // ---- K loop: 8 static steps, no barriers. 3-deep ring: step ks consumes
    //      S[ks%3]; refilled for step ks+3. ----
    #pragma unroll
    for (int ks = 0; ks < 8; ++ks) {
      short8 af[4];
      #pragma unroll
      for (int m = 0; m < 4; ++m)
        af[m] = *(const short8*)((const char*)As + (m * 8 + ks) * 1024 + lane * 16);
      __builtin_amdgcn_s_setprio(1);
      #pragma unroll
      for (int n = 0; n < 4; ++n)
        #pragma unroll
        for (int m = 0; m < 4; ++m)
          acc[m][n] = __builtin_amdgcn_mfma_f32_16x16x32_bf16(af[m], S[ks % 3][n], acc[m][n], 0, 0, 0);
      __builtin_amdgcn_s_setprio(0);
      if (ks < 5) {                              // refill consumed slot for ks+3
        #pragma unroll
        for (int n = 0; n < 4; ++n)
          S[ks % 3][n] = *(const short8*)(pb + n * 8192 + (ks + 3) * 1024);
      }
    }

    // ---- refill ring for tile 1 NOW (S is dead); hides under the epilogue ----
    if (j == 0) {
      #pragma unroll
      for (int s = 0; s < 3; ++s)
        #pragma unroll
        for (int n = 0; n < 4; ++n)
          S[s][n] = *(const short8*)(pb1 + n * 8192 + s * 1024);
    }

    // ---- tile-j epilogue: PURE VALU/LDS (no vmem -> doesn't block S fill).
    // E = exp2(acc); rows -> rowsum LDS (owner-lane add), cols -> colsum LDS.
    // C/D layout: col = n*16 + lo16, row = m*16 + q4*4 + g.
    float colpart[4] = {0.f, 0.f, 0.f, 0.f};
    float rp[4][4];
    #pragma unroll
    for (int m = 0; m < 4; ++m)
      #pragma unroll
      for (int g = 0; g < 4; ++g)
        rp[m][g] = 0.0f;

    #pragma unroll
    for (int m = 0; m < 4; ++m)
      #pragma unroll
      for (int n = 0; n < 4; ++n)
        #pragma unroll
        for (int g = 0; g < 4; ++g) {
          float ev = __builtin_amdgcn_exp2f(acc[m][n][g]);
          rp[m][g] += ev;
          colpart[n] += ev;
        }

    #pragma unroll
    for (int m = 0; m < 4; ++m)
      #pragma unroll
      for (int g = 0; g < 4; ++g) {
        float rs = rp[m][g];
        rs += __shfl_xor(rs, 1);
        rs += __shfl_xor(rs, 2);
        rs += __shfl_xor(rs, 4);
        rs += __shfl_xor(rs, 8);
        if (lo16 == m * 4 + g) {
          int r = m * 16 + q4 * 4 + g;
          if (j == 0) rowsum[w][r] = rs;
          else        rowsum[w][r] += rs;          // same owner lane, no race
        }
      }

    #pragma unroll
    for (int n = 0; n < 4; ++n) {
      float cs = colpart[n];
      cs += __shfl_xor(cs, 16);
      cs += __shfl_xor(cs, 32);
      if (q4 == n) {
        colsum[j * 256 + w * 64 + n * 16 + lo16] = cs;   // written exactly once
      }
    }
  }

  __syncthreads();

  // ---- tail: all global atomics in one dependent-free burst ----
  atomicAdd(&out[NB + colblk * 512 + tid], colsum[tid]);
  atomicAdd(&out[NB + colblk * 512 + 256 + tid], colsum[256 + tid]);
  if (tid < 64) {
    float s = rowsum[0][tid] + rowsum[1][tid] + rowsum[2][tid] + rowsum[3][tid];
    atomicAdd(&out[rowblk * 64 + tid], s);
  }
}

extern "C" void kernel_launch(void* const* d_in, const int* in_sizes, int n_in,
                              void* d_out, int out_size, void* d_ws, size_t ws_size,
                              hipStream_t stream) {
  const float* e = (const float*)d_in[0];
  const float* v = (const float*)d_in[1];
  float* out = (float*)d_out;
  unsigned short* apk = (unsigned short*)d_ws;                 // 4 MiB packed e
  unsigned short* vpk = apk + (size_t)NB * DK;                 // 4 MiB packed v
  hipLaunchKernelGGL(normpack_kernel, dim3((2 * NB) / 4), dim3(256), 0, stream, e, v, apk, vpk, out);
  hipLaunchKernelGGL(score_kernel, dim3(2048), dim3(256), 0, stream, apk, vpk, out);
}